// Round 2
// baseline (314.523 us; speedup 1.0000x reference)
//
#include <hip/hip_runtime.h>
#include <math.h>

#define NEAR0f 1e-8f
#define REGf   0.002f

typedef float __attribute__((ext_vector_type(4))) f32x4;
typedef int   __attribute__((ext_vector_type(4))) i32x4;

__device__ __forceinline__ float wave_reduce(float v) {
#pragma unroll
    for (int off = 32; off > 0; off >>= 1)
        v += __shfl_down(v, off, 64);
    return v;
}

// sum of log(selected prob) over 4 elements, tree-summed
__device__ __forceinline__ float nll4(f32x4 p, i32x4 l) {
    float a0 = l.x ? p.x : 1.0f - p.x;
    float a1 = l.y ? p.y : 1.0f - p.y;
    float a2 = l.z ? p.z : 1.0f - p.z;
    float a3 = l.w ? p.w : 1.0f - p.w;
    float g0 = __logf(fmaxf(a0, NEAR0f)) + __logf(fmaxf(a1, NEAR0f));
    float g1 = __logf(fmaxf(a2, NEAR0f)) + __logf(fmaxf(a3, NEAR0f));
    return g0 + g1;
}

__device__ __forceinline__ float sq4(f32x4 a, float acc) {
    return fmaf(a.x, a.x, fmaf(a.y, a.y, fmaf(a.z, a.z, fmaf(a.w, a.w, acc))));
}

// R2 theory: R1 showed occupancy 22->56% with ZERO throughput gain and
// VGPR_Count=28 -- the compiler serialized the "batched" loads (8 live f32x4
// need 32 VGPRs alone; at 28 total they can't coexist). Fix = per-wave MLP:
//  - straight-line fast path, no loop: 8 (p,l) pairs + 4 w loads per thread,
//    ALL issued before any consume (sched_barrier(0) fences the phases),
//    launch_bounds(256,4) -> 128 VGPR budget, ~18 loads in flight per wave.
//  - finalize fused in (launch overhead ~15 us/kernel measured R0->R1):
//    CAS-unpoison (ws poisoned 0xAA each launch) + float atomicAdd partials
//    + poison-based completion counter; last block writes out[0].
__global__ __launch_bounds__(256, 4) void fused(
    const f32x4* __restrict__ p4,
    const i32x4* __restrict__ l4,
    const f32x4* __restrict__ w1,
    const f32x4* __restrict__ w2,
    float* __restrict__ acc,      // [0..2] sums, bytes 16..23 = u64 counter
    float* __restrict__ out,
    float invN,
    int n4, int w4)
{
    const int tid    = blockIdx.x * blockDim.x + threadIdx.x;
    const int stride = gridDim.x * blockDim.x;

    float nll, s1, s2;

    if (n4 == 8 * stride && w4 == 2 * stride) {
        // ---- fast path: exact tiling, straight-line, max MLP ----
        const f32x4* P = p4 + tid;
        const i32x4* L = l4 + tid;

        f32x4 pv[8];
        i32x4 lv[8];
#pragma unroll
        for (int k = 0; k < 8; ++k) {
            pv[k] = P[(size_t)k * stride];
            lv[k] = L[(size_t)k * stride];
        }
        f32x4 a0 = w1[tid];
        f32x4 a1 = w1[tid + stride];
        f32x4 b0 = w2[tid];
        f32x4 b1 = w2[tid + stride];
        // fence: all 20 loads issued before any consumer is scheduled
        __builtin_amdgcn_sched_barrier(0);

        float t[8];
#pragma unroll
        for (int k = 0; k < 8; ++k) t[k] = nll4(pv[k], lv[k]);
        nll = -((((t[0] + t[1]) + (t[2] + t[3])) + ((t[4] + t[5]) + (t[6] + t[7]))));

        float s1a = sq4(a0, 0.0f), s1b = sq4(a1, 0.0f);
        float s2a = sq4(b0, 0.0f), s2b = sq4(b1, 0.0f);
        s1 = s1a + s1b;
        s2 = s2a + s2b;
    } else {
        // ---- generic fallback (grid-stride) ----
        float nll0 = 0.0f;
        for (int i = tid; i < n4; i += stride)
            nll0 -= nll4(p4[i], l4[i]);
        nll = nll0;
        float s1a = 0.0f, s2a = 0.0f;
        for (int j = tid; j < w4; j += stride) {
            s1a = sq4(w1[j], s1a);
            s2a = sq4(w2[j], s2a);
        }
        s1 = s1a;
        s2 = s2a;
    }

    nll = wave_reduce(nll);
    s1  = wave_reduce(s1);
    s2  = wave_reduce(s2);

    __shared__ float sm[3][4];
    const int lane = threadIdx.x & 63;
    const int wave = threadIdx.x >> 6;
    if (lane == 0) { sm[0][wave] = nll; sm[1][wave] = s1; sm[2][wave] = s2; }
    __syncthreads();

    if (threadIdx.x == 0) {
        const float bn = sm[0][0] + sm[0][1] + sm[0][2] + sm[0][3];
        const float b1 = sm[1][0] + sm[1][1] + sm[1][2] + sm[1][3];
        const float b2 = sm[2][0] + sm[2][1] + sm[2][2] + sm[2][3];

        // un-poison accumulators exactly once (one CAS winner flips 0xAA.. -> 0)
        unsigned int* ubits = reinterpret_cast<unsigned int*>(acc);
        atomicCAS(&ubits[0], 0xAAAAAAAAu, 0u);
        atomicCAS(&ubits[1], 0xAAAAAAAAu, 0u);
        atomicCAS(&ubits[2], 0xAAAAAAAAu, 0u);
        atomicAdd(&acc[0], bn);
        atomicAdd(&acc[1], b1);
        atomicAdd(&acc[2], b2);

        __threadfence();
        unsigned long long* cnt = reinterpret_cast<unsigned long long*>(acc + 4);
        const unsigned long long prev = atomicAdd(cnt, 1ull);
        // counter starts at poison 0xAAAA..AA; last arrival sees poison+grid-1
        if (prev == 0xAAAAAAAAAAAAAAAAull + (unsigned long long)gridDim.x - 1ull) {
            __threadfence();
            const float tn = __hip_atomic_load(&acc[0], __ATOMIC_ACQUIRE, __HIP_MEMORY_SCOPE_AGENT);
            const float t1 = __hip_atomic_load(&acc[1], __ATOMIC_ACQUIRE, __HIP_MEMORY_SCOPE_AGENT);
            const float t2 = __hip_atomic_load(&acc[2], __ATOMIC_ACQUIRE, __HIP_MEMORY_SCOPE_AGENT);
            out[0] = tn * invN + REGf * (sqrtf(t1) + sqrtf(t2));
        }
    }
}

extern "C" void kernel_launch(void* const* d_in, const int* in_sizes, int n_in,
                              void* d_out, int out_size, void* d_ws, size_t ws_size,
                              hipStream_t stream) {
    const float* out1  = (const float*)d_in[0];   // [N,1] fp32
    const int*   label = (const int*)d_in[1];     // [N] int32 (jax x64 off)
    const float* W1    = (const float*)d_in[2];   // [1024,4096] fp32
    const float* W2    = (const float*)d_in[3];   // [4096,1024] fp32

    const int N  = in_sizes[0];
    const int n4 = N / 4;
    const int w4 = in_sizes[2] / 4;               // W1 and W2 same size

    const int NBLK = 2048;                        // exact tiling: 8 p/l + 2+2 w per thread
    fused<<<NBLK, 256, 0, stream>>>(
        (const f32x4*)out1, (const i32x4*)label,
        (const f32x4*)W1,   (const f32x4*)W2,
        (float*)d_ws, (float*)d_out, 1.0f / (float)N, n4, w4);
}

// Round 3
// 192.828 us; speedup vs baseline: 1.6311x; 1.6311x over previous
//
#include <hip/hip_runtime.h>
#include <math.h>

#define NEAR0f 1e-8f
#define REGf   0.002f

typedef float __attribute__((ext_vector_type(4))) f32x4;
typedef int   __attribute__((ext_vector_type(4))) i32x4;

__device__ __forceinline__ float wave_reduce(float v) {
#pragma unroll
    for (int off = 32; off > 0; off >>= 1)
        v += __shfl_down(v, off, 64);
    return v;
}

// sum of log(selected prob) over 4 elements, tree-summed
__device__ __forceinline__ float nll4(f32x4 p, i32x4 l) {
    float a0 = l.x ? p.x : 1.0f - p.x;
    float a1 = l.y ? p.y : 1.0f - p.y;
    float a2 = l.z ? p.z : 1.0f - p.z;
    float a3 = l.w ? p.w : 1.0f - p.w;
    float g0 = __logf(fmaxf(a0, NEAR0f)) + __logf(fmaxf(a1, NEAR0f));
    float g1 = __logf(fmaxf(a2, NEAR0f)) + __logf(fmaxf(a3, NEAR0f));
    return g0 + g1;
}

__device__ __forceinline__ float sq4(f32x4 a, float acc) {
    return fmaf(a.x, a.x, fmaf(a.y, a.y, fmaf(a.z, a.z, fmaf(a.w, a.w, acc))));
}

// R3: revert to R0 shell (1024 blocks, 3 launches, per-block atomics -- proven
// 59 us kernel; launches inside the graph cost ~1-3 us, R2's fused-atomic tail
// cost 145 us). Core change: force >=16 loads in flight per wave via ONE asm
// block (16x global_load_dwordx4 saddr+voffset, s_waitcnt vmcnt(0) inside,
// results as "=v" outputs). Compiler rewrote every source-level batching
// attempt to ~4 in flight (VGPR 28-44 across R0-R2); asm outputs force 64
// data VGPRs live. This is the decisive MLP-theory test: VGPR ~100 + no
// speedup = structural ceiling; VGPR ~100 + speedup = latency was the limit.
__global__ __launch_bounds__(256, 4) void reduce_all(
    const float* __restrict__ pB,
    const int*   __restrict__ lB,
    const float* __restrict__ w1B,
    const float* __restrict__ w2B,
    float* __restrict__ acc,
    int n4, int w4)
{
    const int tid    = blockIdx.x * blockDim.x + threadIdx.x;
    const int stride = gridDim.x * blockDim.x;

    float nll = 0.0f, s1 = 0.0f, s2 = 0.0f;

    if (n4 == 16 * stride && w4 == 4 * stride) {
        // exact tiling: 16 (p,l) x4-pairs + 4 w1 + 4 w2 x4 per thread
        const unsigned base = (unsigned)tid * 16u;      // byte offset
        const unsigned step = (unsigned)stride * 16u;   // 4 MiB

        float nA = 0.0f, nB = 0.0f, nC = 0.0f, nD = 0.0f;
#pragma unroll
        for (int b = 0; b < 2; ++b) {
            const unsigned o0 = base + (unsigned)(8 * b) * step;
            const unsigned o1 = o0 + step;
            const unsigned o2 = o0 + 2u * step;
            const unsigned o3 = o0 + 3u * step;
            const unsigned o4 = o0 + 4u * step;
            const unsigned o5 = o0 + 5u * step;
            const unsigned o6 = o0 + 6u * step;
            const unsigned o7 = o0 + 7u * step;
            f32x4 p0, p1, p2, p3, p4, p5, p6, p7;
            i32x4 l0, l1, l2, l3, l4, l5, l6, l7;
            asm volatile(
                "global_load_dwordx4 %0, %16, %24\n\t"
                "global_load_dwordx4 %8, %16, %25\n\t"
                "global_load_dwordx4 %1, %17, %24\n\t"
                "global_load_dwordx4 %9, %17, %25\n\t"
                "global_load_dwordx4 %2, %18, %24\n\t"
                "global_load_dwordx4 %10, %18, %25\n\t"
                "global_load_dwordx4 %3, %19, %24\n\t"
                "global_load_dwordx4 %11, %19, %25\n\t"
                "global_load_dwordx4 %4, %20, %24\n\t"
                "global_load_dwordx4 %12, %20, %25\n\t"
                "global_load_dwordx4 %5, %21, %24\n\t"
                "global_load_dwordx4 %13, %21, %25\n\t"
                "global_load_dwordx4 %6, %22, %24\n\t"
                "global_load_dwordx4 %14, %22, %25\n\t"
                "global_load_dwordx4 %7, %23, %24\n\t"
                "global_load_dwordx4 %15, %23, %25\n\t"
                "s_waitcnt vmcnt(0)"
                : "=v"(p0), "=v"(p1), "=v"(p2), "=v"(p3),
                  "=v"(p4), "=v"(p5), "=v"(p6), "=v"(p7),
                  "=v"(l0), "=v"(l1), "=v"(l2), "=v"(l3),
                  "=v"(l4), "=v"(l5), "=v"(l6), "=v"(l7)
                : "v"(o0), "v"(o1), "v"(o2), "v"(o3),
                  "v"(o4), "v"(o5), "v"(o6), "v"(o7),
                  "s"(pB), "s"(lB)
                : "memory");
            nA -= nll4(p0, l0); nB -= nll4(p1, l1);
            nC -= nll4(p2, l2); nD -= nll4(p3, l3);
            nA -= nll4(p4, l4); nB -= nll4(p5, l5);
            nC -= nll4(p6, l6); nD -= nll4(p7, l7);
        }
        nll = (nA + nB) + (nC + nD);

        {
            const unsigned o0 = base;
            const unsigned o1 = base + step;
            const unsigned o2 = base + 2u * step;
            const unsigned o3 = base + 3u * step;
            f32x4 a0, a1, a2, a3, b0, b1, b2, b3;
            asm volatile(
                "global_load_dwordx4 %0, %8, %12\n\t"
                "global_load_dwordx4 %4, %8, %13\n\t"
                "global_load_dwordx4 %1, %9, %12\n\t"
                "global_load_dwordx4 %5, %9, %13\n\t"
                "global_load_dwordx4 %2, %10, %12\n\t"
                "global_load_dwordx4 %6, %10, %13\n\t"
                "global_load_dwordx4 %3, %11, %12\n\t"
                "global_load_dwordx4 %7, %11, %13\n\t"
                "s_waitcnt vmcnt(0)"
                : "=v"(a0), "=v"(a1), "=v"(a2), "=v"(a3),
                  "=v"(b0), "=v"(b1), "=v"(b2), "=v"(b3)
                : "v"(o0), "v"(o1), "v"(o2), "v"(o3),
                  "s"(w1B), "s"(w2B)
                : "memory");
            float s1a = sq4(a0, 0.0f), s1b = sq4(a1, 0.0f);
            s1a = sq4(a2, s1a); s1b = sq4(a3, s1b);
            float s2a = sq4(b0, 0.0f), s2b = sq4(b1, 0.0f);
            s2a = sq4(b2, s2a); s2b = sq4(b3, s2b);
            s1 = s1a + s1b;
            s2 = s2a + s2b;
        }
    } else {
        // generic fallback (grid-stride, plain C)
        const f32x4* p4v = (const f32x4*)pB;
        const i32x4* l4v = (const i32x4*)lB;
        const f32x4* w1v = (const f32x4*)w1B;
        const f32x4* w2v = (const f32x4*)w2B;
        for (int i = tid; i < n4; i += stride) nll -= nll4(p4v[i], l4v[i]);
        for (int j = tid; j < w4; j += stride) {
            s1 = sq4(w1v[j], s1);
            s2 = sq4(w2v[j], s2);
        }
    }

    nll = wave_reduce(nll);
    s1  = wave_reduce(s1);
    s2  = wave_reduce(s2);

    __shared__ float sm[3][4];
    const int lane = threadIdx.x & 63;
    const int wave = threadIdx.x >> 6;
    if (lane == 0) { sm[0][wave] = nll; sm[1][wave] = s1; sm[2][wave] = s2; }
    __syncthreads();
    if (threadIdx.x == 0) {
        atomicAdd(&acc[0], sm[0][0] + sm[0][1] + sm[0][2] + sm[0][3]);
        atomicAdd(&acc[1], sm[1][0] + sm[1][1] + sm[1][2] + sm[1][3]);
        atomicAdd(&acc[2], sm[2][0] + sm[2][1] + sm[2][2] + sm[2][3]);
    }
}

// d_ws is poisoned 0xAA before every launch — zero accumulators ourselves.
__global__ void init_acc(float* acc) {
    acc[0] = 0.0f; acc[1] = 0.0f; acc[2] = 0.0f;
}

__global__ void finalize(const float* __restrict__ acc, float* __restrict__ out,
                         float invN) {
    out[0] = acc[0] * invN + REGf * (sqrtf(acc[1]) + sqrtf(acc[2]));
}

extern "C" void kernel_launch(void* const* d_in, const int* in_sizes, int n_in,
                              void* d_out, int out_size, void* d_ws, size_t ws_size,
                              hipStream_t stream) {
    const float* out1  = (const float*)d_in[0];   // [N,1] fp32
    const int*   label = (const int*)d_in[1];     // [N] int32 (jax x64 off)
    const float* W1    = (const float*)d_in[2];   // [1024,4096] fp32
    const float* W2    = (const float*)d_in[3];   // [4096,1024] fp32

    const int N  = in_sizes[0];
    const int n4 = N / 4;
    const int w4 = in_sizes[2] / 4;               // W1 and W2 same size

    float* acc = (float*)d_ws;

    init_acc<<<1, 1, 0, stream>>>(acc);
    // 1024 blocks x 256 threads: exact tiling (16 p/l pairs + 4+4 w per
    // thread), 4 blocks/CU at launch_bounds(256,4) -> 128 VGPR budget.
    reduce_all<<<1024, 256, 0, stream>>>(
        out1, label, W1, W2, acc, n4, w4);
    finalize<<<1, 1, 0, stream>>>(acc, (float*)d_out, 1.0f / (float)N);
}